// Round 9
// baseline (368.814 us; speedup 1.0000x reference)
//
#include <hip/hip_runtime.h>

#define B_DIM 4096
#define T_DIM 200
#define D_DIM 128
#define H_DIM 16
#define BPB   16          // b's per block
#define NBLK  (B_DIM/BPB) // 256 blocks = 1 per CU

__device__ __forceinline__ float bflo(unsigned int u){ return __uint_as_float(u << 16); }
__device__ __forceinline__ float bfhi(unsigned int u){ return __uint_as_float(u & 0xffff0000u); }
__device__ __forceinline__ unsigned int pk_bf16(float a, float b){
    unsigned int ua = __float_as_uint(a), ub = __float_as_uint(b);
    unsigned int ra = (ua + 0x7fffu + ((ua >> 16) & 1u)) >> 16;
    unsigned int rb = (ub + 0x7fffu + ((ub >> 16) & 1u)) & 0xffff0000u;
    return rb | ra;
}

extern "C" __global__ __launch_bounds__(1024)
void din_fused(const float* __restrict__ query,
               const float* __restrict__ facts,
               const int* __restrict__ mask,
               const float* __restrict__ W1,
               const float* __restrict__ b1,
               const float* __restrict__ W2,
               float* __restrict__ out)
{
    const int tid  = threadIdx.x;
    const int wid  = tid >> 6;        // 0..15
    const int lane = tid & 63;
    const int sub  = lane & 7;        // d-octant: owns d = {64k + 8*sub + c}
    const int rg   = lane >> 3;       // rowgroup within wave (0..7)
    const int b0   = blockIdx.x * BPB;

    __shared__ float W1bc[H_DIM * D_DIM];          // (W1b - W1c)[h][d]
    __shared__ float W1dd[H_DIM * D_DIM];          // W1d[h][d]
    __shared__ unsigned int weffp[H_DIM * 64];     // bf16x2-packed weff [h][d/2]
    __shared__ float qwl[BPB * H_DIM];             // per-b qw
    __shared__ float sacc[16 * D_DIM];             // per-wave PV partials
    __shared__ float redm[16], redl[16];

    // lane's h after the halving reduce: h = bitrev3(sub)
    const int hA = ((sub & 1) << 2) | (sub & 2) | ((sub >> 2) & 1);
    const int hB = hA + 8;
    const float w2A = W2[hA], w2B = W2[hB];

    const int row = wid * 16 + rg * 2;             // this thread's rows: row, row+1
    const int r0c = (row     < T_DIM) ? row     : T_DIM - 1;
    const int r1c = (row + 1 < T_DIM) ? row + 1 : T_DIM - 1;

    auto loadFR = [&](int b, float4 (&F)[2][4], int (&mv)[2]) {
        const float* fb = facts + (size_t)b * (T_DIM * D_DIM);
        #pragma unroll
        for (int k = 0; k < 2; ++k) {
            F[0][2*k    ] = *(const float4*)(fb + r0c * D_DIM + 64*k + 8*sub);
            F[0][2*k + 1] = *(const float4*)(fb + r0c * D_DIM + 64*k + 8*sub + 4);
            F[1][2*k    ] = *(const float4*)(fb + r1c * D_DIM + 64*k + 8*sub);
            F[1][2*k + 1] = *(const float4*)(fb + r1c * D_DIM + 64*k + 8*sub + 4);
        }
        mv[0] = (row     < T_DIM) ? mask[(size_t)b * T_DIM + r0c] : 0;
        mv[1] = (row + 1 < T_DIM) ? mask[(size_t)b * T_DIM + r1c] : 0;
    };

    // ================= prologue =================
    float4 FRA[2][4], FRB[2][4];
    int mvA[2], mvB[2];
    loadFR(b0, FRA, mvA);                          // HBM latency hides under setup below

    {   // transpose W1 quadrants b,c,d into LDS (once per block)
        int e = tid * 2, h = e >> 7, d = e & 127;
        float vb0 = W1[(128 + d) * H_DIM + h], vc0 = W1[(256 + d) * H_DIM + h];
        float vd0 = W1[(384 + d) * H_DIM + h];
        float vb1 = W1[(129 + d) * H_DIM + h], vc1 = W1[(257 + d) * H_DIM + h];
        float vd1 = W1[(385 + d) * H_DIM + h];
        W1bc[h * D_DIM + d]     = vb0 - vc0;
        W1bc[h * D_DIM + d + 1] = vb1 - vc1;
        W1dd[h * D_DIM + d]     = vd0;
        W1dd[h * D_DIM + d + 1] = vd1;
    }
    {   // qw for all 16 b's of this block: thread = (bi=wid, h, grp of 32 d)
        int bi = tid >> 6, h = (tid >> 2) & 15, grp = tid & 3;
        const float* q = query + (size_t)(b0 + bi) * D_DIM + grp * 32;
        float p = 0.f;
        #pragma unroll
        for (int d = 0; d < 32; ++d) {
            int dd = grp * 32 + d;
            p += q[d] * (W1[dd * H_DIM + h] + W1[(256 + dd) * H_DIM + h]);
        }
        p += __shfl_xor(p, 1);
        p += __shfl_xor(p, 2);
        if (grp == 0) qwl[bi * H_DIM + h] = p + b1[h];
    }
    __syncthreads();

    // ================= one pipelined step =================
    auto step = [&](int b, int ii, float4 (&FC)[2][4], int (&mvC)[2],
                    float4 (&FN)[2][4], int (&mvN)[2]) {
        // ---- weff (bf16-packed) for this b ----
        {
            int h = tid >> 6, dp = tid & 63, d = dp * 2;
            float2 q2 = *(const float2*)(query + (size_t)b * D_DIM + d);
            float2 bc = *(const float2*)(&W1bc[h * D_DIM + d]);
            float2 dd = *(const float2*)(&W1dd[h * D_DIM + d]);
            weffp[h * 64 + dp] = pk_bf16(bc.x + q2.x * dd.x, bc.y + q2.y * dd.y);
        }
        if (ii + 1 < BPB) loadFR(b + 1, FN, mvN);   // prefetch next b (overlaps everything)
        __syncthreads();                            // B2: weff ready

        const float qwA = qwl[ii * H_DIM + hA];
        const float qwB = qwl[ii * H_DIM + hB];

        // ---- scoring: 16 h in 2 batches, halving-reduce over the 8 sub lanes ----
        float spart[2] = {0.f, 0.f};
        #pragma unroll
        for (int bb = 0; bb < 2; ++bb) {
            float hp[2][8];
            #pragma unroll
            for (int r = 0; r < 2; ++r)
                #pragma unroll
                for (int i = 0; i < 8; ++i) hp[r][i] = 0.f;
            #pragma unroll
            for (int k = 0; k < 2; ++k) {
                #pragma unroll
                for (int i = 0; i < 8; ++i) {
                    uint4 wp = *(const uint4*)&weffp[(8*bb + i) * 64 + 32*k + 4*sub];
                    float u0 = bflo(wp.x), u1 = bfhi(wp.x);
                    float u2 = bflo(wp.y), u3 = bfhi(wp.y);
                    float u4 = bflo(wp.z), u5 = bfhi(wp.z);
                    float u6 = bflo(wp.w), u7 = bfhi(wp.w);
                    #pragma unroll
                    for (int r = 0; r < 2; ++r) {
                        hp[r][i] += u0 * FC[r][2*k].x + u1 * FC[r][2*k].y
                                  + u2 * FC[r][2*k].z + u3 * FC[r][2*k].w
                                  + u4 * FC[r][2*k+1].x + u5 * FC[r][2*k+1].y
                                  + u6 * FC[r][2*k+1].z + u7 * FC[r][2*k+1].w;
                    }
                }
            }
            // halving reduce over sub: lane ends with h = 8*bb + bitrev3(sub), full 128-d sum
            #pragma unroll
            for (int r = 0; r < 2; ++r) {
                #pragma unroll
                for (int i = 0; i < 4; ++i) {
                    float kp = (sub & 1) ? hp[r][i+4] : hp[r][i];
                    float sd = (sub & 1) ? hp[r][i]   : hp[r][i+4];
                    hp[r][i] = kp + __shfl_xor(sd, 1);
                }
                #pragma unroll
                for (int i = 0; i < 2; ++i) {
                    float kp = (sub & 2) ? hp[r][i+2] : hp[r][i];
                    float sd = (sub & 2) ? hp[r][i]   : hp[r][i+2];
                    hp[r][i] = kp + __shfl_xor(sd, 2);
                }
                float kp = (sub & 4) ? hp[r][1] : hp[r][0];
                float sd = (sub & 4) ? hp[r][0] : hp[r][1];
                hp[r][0] = kp + __shfl_xor(sd, 4);
            }
            float qws = bb ? qwB : qwA;
            float w2s = bb ? w2B : w2A;
            #pragma unroll
            for (int r = 0; r < 2; ++r)
                spart[r] += w2s / (1.f + __expf(-(qws + hp[r][0])));
        }
        float score[2];
        #pragma unroll
        for (int r = 0; r < 2; ++r) {
            float s = spart[r];
            s += __shfl_xor(s, 1);
            s += __shfl_xor(s, 2);
            s += __shfl_xor(s, 4);
            score[r] = mvC[r] ? s : -1e30f;
        }

        // ---- per-wave softmax over its 16 rows ----
        float mloc = fmaxf(score[0], score[1]);
        mloc = fmaxf(mloc, __shfl_xor(mloc, 8));
        mloc = fmaxf(mloc, __shfl_xor(mloc, 16));
        mloc = fmaxf(mloc, __shfl_xor(mloc, 32));
        float w0 = mvC[0] ? __expf(score[0] - mloc) : 0.f;
        float w1 = mvC[1] ? __expf(score[1] - mloc) : 0.f;
        float ls = w0 + w1;
        ls += __shfl_xor(ls, 8);
        ls += __shfl_xor(ls, 16);
        ls += __shfl_xor(ls, 32);

        // ---- PV: weighted rows, halving-reduce over the 8 rowgroups ----
        float a[16];
        #pragma unroll
        for (int j = 0; j < 4; ++j) {
            a[4*j+0] = w0 * FC[0][j].x + w1 * FC[1][j].x;
            a[4*j+1] = w0 * FC[0][j].y + w1 * FC[1][j].y;
            a[4*j+2] = w0 * FC[0][j].z + w1 * FC[1][j].z;
            a[4*j+3] = w0 * FC[0][j].w + w1 * FC[1][j].w;
        }
        #pragma unroll
        for (int i = 0; i < 8; ++i) {
            float kp = (rg & 1) ? a[i+8] : a[i];
            float sd = (rg & 1) ? a[i]   : a[i+8];
            a[i] = kp + __shfl_xor(sd, 8);
        }
        #pragma unroll
        for (int i = 0; i < 4; ++i) {
            float kp = (rg & 2) ? a[i+4] : a[i];
            float sd = (rg & 2) ? a[i]   : a[i+4];
            a[i] = kp + __shfl_xor(sd, 16);
        }
        #pragma unroll
        for (int i = 0; i < 2; ++i) {
            float kp = (rg & 4) ? a[i+2] : a[i];
            float sd = (rg & 4) ? a[i]   : a[i+2];
            a[i] = kp + __shfl_xor(sd, 32);
        }
        int d0 = 64*(rg & 1) + 8*sub + 4*((rg >> 1) & 1) + 2*((rg >> 2) & 1);
        *(float2*)&sacc[wid * D_DIM + d0] = make_float2(a[0], a[1]);
        if (lane == 0) { redm[wid] = mloc; redl[wid] = ls; }
        __syncthreads();                            // B1: sacc/red ready

        // ---- merge 16 wave partials, store ----
        if (tid < D_DIM) {
            float M = redm[0];
            #pragma unroll
            for (int i2 = 1; i2 < 16; ++i2) M = fmaxf(M, redm[i2]);
            float L = 0.f, o = 0.f;
            #pragma unroll
            for (int i2 = 0; i2 < 16; ++i2) {
                float e = __expf(redm[i2] - M);
                L += e * redl[i2];
                o += e * sacc[i2 * D_DIM + tid];
            }
            out[(size_t)b * D_DIM + tid] = o / L;
        }
        // no barrier here: next step only writes weffp (disjoint) before its B2
    };

    // ================= main pipelined loop =================
    #pragma unroll 1
    for (int ii = 0; ii < BPB; ii += 2) {
        step(b0 + ii,     ii,     FRA, mvA, FRB, mvB);
        step(b0 + ii + 1, ii + 1, FRB, mvB, FRA, mvA);
    }
}

extern "C" void kernel_launch(void* const* d_in, const int* in_sizes, int n_in,
                              void* d_out, int out_size, void* d_ws, size_t ws_size,
                              hipStream_t stream) {
    const float* query = (const float*)d_in[0];
    const float* facts = (const float*)d_in[1];
    const int*   mask  = (const int*)d_in[2];   // harness delivers bool as int32
    const float* W1    = (const float*)d_in[3];
    const float* b1    = (const float*)d_in[4];
    const float* W2    = (const float*)d_in[5];
    // d_in[6] = b2: dropped (softmax shift-invariant)
    float* out = (float*)d_out;
    (void)in_sizes; (void)n_in; (void)out_size; (void)d_ws; (void)ws_size;

    din_fused<<<dim3(NBLK), dim3(1024), 0, stream>>>(
        query, facts, mask, W1, b1, W2, out);
}

// Round 10
// 347.661 us; speedup vs baseline: 1.0608x; 1.0608x over previous
//
#include <hip/hip_runtime.h>

#define B_DIM 4096
#define T_DIM 200
#define D_DIM 128
#define H_DIM 16
#define NCH   13    // chunks of 16 rows (13*16 = 208 >= 200)

__device__ __forceinline__ float bflo(unsigned int u){ return __uint_as_float(u << 16); }
__device__ __forceinline__ float bfhi(unsigned int u){ return __uint_as_float(u & 0xffff0000u); }
__device__ __forceinline__ unsigned int pk_bf16(float a, float b){
    unsigned int ua = __float_as_uint(a), ub = __float_as_uint(b);
    unsigned int ra = (ua + 0x7fffu + ((ua >> 16) & 1u)) >> 16;
    unsigned int rb = (ub + 0x7fffu + ((ub >> 16) & 1u)) & 0xffff0000u;
    return rb | ra;
}

extern "C" __global__ __launch_bounds__(512)
void din_fused(const float* __restrict__ query,
               const float* __restrict__ facts,
               const int* __restrict__ mask,
               const float* __restrict__ W1,
               const float* __restrict__ b1,
               const float* __restrict__ W2,
               float* __restrict__ out)
{
    const int tid  = threadIdx.x;
    const int wid  = tid >> 6;        // 0..7 : wave = one b
    const int lane = tid & 63;
    const int sub  = lane & 7;        // d-octant: owns d = sub*16 .. +15
    const int rg   = lane >> 3;       // rowgroup: rows c*16 + 2*rg, +1
    const int b    = blockIdx.x * 8 + wid;

    __shared__ float W1bc[H_DIM * D_DIM];        // (W1b - W1c)[h][d]
    __shared__ float W1dd[H_DIM * D_DIM];        // W1d[h][d]
    __shared__ float W1ac[H_DIM * D_DIM];        // (W1a + W1c)[h][d]
    __shared__ unsigned int weffp[8][H_DIM * 64];// per-wave bf16x2 weff [h][d/2]
    __shared__ float qwl[8][H_DIM];              // per-wave qw

    const float* fb = facts + (size_t)b * (T_DIM * D_DIM);
    const int*   mb = mask  + (size_t)b * T_DIM;
    const float* qb = query + (size_t)b * D_DIM;

    // ---- issue chunk-0 facts loads FIRST (latency hides under whole prologue) ----
    float4 FA[2][4], FB[2][4];
    int mvA[2], mvB[2];
    auto loadFR = [&](int c, float4 (&F)[2][4], int (&mv)[2]) {
        int r0 = c * 16 + 2 * rg, r1 = r0 + 1;
        int r0c = r0 < T_DIM ? r0 : T_DIM - 1;
        int r1c = r1 < T_DIM ? r1 : T_DIM - 1;
        #pragma unroll
        for (int k = 0; k < 4; ++k) {
            F[0][k] = *(const float4*)(fb + r0c * D_DIM + sub * 16 + 4 * k);
            F[1][k] = *(const float4*)(fb + r1c * D_DIM + sub * 16 + 4 * k);
        }
        mv[0] = (r0 < T_DIM) ? mb[r0c] : 0;
        mv[1] = (r1 < T_DIM) ? mb[r1c] : 0;
    };
    loadFR(0, FA, mvA);

    // ---- one-time W1 transpose into LDS (only block-wide barrier in the kernel) ----
    #pragma unroll
    for (int i = 0; i < 4; ++i) {
        int idx = tid * 4 + i;                    // 0..2047 = h*128 + d
        int h = idx >> 7, d = idx & 127;
        W1bc[idx] = W1[(128 + d) * H_DIM + h] - W1[(256 + d) * H_DIM + h];
        W1dd[idx] = W1[(384 + d) * H_DIM + h];
        W1ac[idx] = W1[d * H_DIM + h] + W1[(256 + d) * H_DIM + h];
    }
    __syncthreads();

    // ---- per-wave qw: lane = (h = lane&15, dgrp = lane>>4) ----
    {
        int h = lane & 15, dg = lane >> 4;
        float p = 0.f;
        #pragma unroll
        for (int k = 0; k < 8; ++k) {
            float4 a4 = *(const float4*)&W1ac[h * D_DIM + dg * 32 + 4 * k];
            float4 q4 = *(const float4*)(qb + dg * 32 + 4 * k);
            p += a4.x * q4.x + a4.y * q4.y + a4.z * q4.z + a4.w * q4.w;
        }
        p += __shfl_xor(p, 16);
        p += __shfl_xor(p, 32);
        if (lane < 16) qwl[wid][h] = p + b1[h];
    }
    // ---- per-wave weff build (bf16-packed): lane covers h=lane>>2, 16 uints ----
    {
        int h = lane >> 2, du0 = (lane & 3) * 16;
        #pragma unroll
        for (int t = 0; t < 4; ++t) {
            unsigned int pk[4];
            #pragma unroll
            for (int u = 0; u < 4; ++u) {
                int d = (du0 + t * 4 + u) * 2;
                float2 q2 = *(const float2*)(qb + d);
                float2 bc = *(const float2*)&W1bc[h * D_DIM + d];
                float2 dd = *(const float2*)&W1dd[h * D_DIM + d];
                pk[u] = pk_bf16(bc.x + q2.x * dd.x, bc.y + q2.y * dd.y);
            }
            *(uint4*)&weffp[wid][h * 64 + du0 + t * 4] = make_uint4(pk[0], pk[1], pk[2], pk[3]);
        }
    }
    // wave-private LDS RAW (same wave wrote it); drain before reads
    asm volatile("s_waitcnt lgkmcnt(0)" ::: "memory");

    // lane's h after halving-reduce: hg (+8 for pass 1)
    const int hg = 4 * (sub & 1) + 2 * ((sub >> 1) & 1) + ((sub >> 2) & 1);
    const float qwA = qwl[wid][hg],     w2A = W2[hg];
    const float qwB = qwl[wid][hg + 8], w2B = W2[hg + 8];
    const unsigned int* wp = &weffp[wid][0];

    float4 acc4[4];
    #pragma unroll
    for (int k = 0; k < 4; ++k) acc4[k] = make_float4(0.f, 0.f, 0.f, 0.f);
    float m = -3e38f, l = 0.f;

    // ---- flash chunk processor: zero barriers, all wave-local ----
    auto process = [&](float4 (&F)[2][4], int (&mv)[2]) {
        float sc0 = 0.f, sc1 = 0.f;
        #pragma unroll
        for (int g = 0; g < 2; ++g) {
            float hp0[8], hp1[8];
            #pragma unroll
            for (int i = 0; i < 8; ++i) {
                uint4 u0 = *(const uint4*)&wp[(g * 8 + i) * 64 + sub * 8];
                uint4 u1 = *(const uint4*)&wp[(g * 8 + i) * 64 + sub * 8 + 4];
                float e0 = bflo(u0.x), e1 = bfhi(u0.x), e2 = bflo(u0.y), e3 = bfhi(u0.y);
                float e4 = bflo(u0.z), e5 = bfhi(u0.z), e6 = bflo(u0.w), e7 = bfhi(u0.w);
                float e8 = bflo(u1.x), e9 = bfhi(u1.x), ea = bflo(u1.y), eb = bfhi(u1.y);
                float ec = bflo(u1.z), ed = bfhi(u1.z), ee = bflo(u1.w), ef = bfhi(u1.w);
                hp0[i] = e0*F[0][0].x + e1*F[0][0].y + e2*F[0][0].z + e3*F[0][0].w
                       + e4*F[0][1].x + e5*F[0][1].y + e6*F[0][1].z + e7*F[0][1].w
                       + e8*F[0][2].x + e9*F[0][2].y + ea*F[0][2].z + eb*F[0][2].w
                       + ec*F[0][3].x + ed*F[0][3].y + ee*F[0][3].z + ef*F[0][3].w;
                hp1[i] = e0*F[1][0].x + e1*F[1][0].y + e2*F[1][0].z + e3*F[1][0].w
                       + e4*F[1][1].x + e5*F[1][1].y + e6*F[1][1].z + e7*F[1][1].w
                       + e8*F[1][2].x + e9*F[1][2].y + ea*F[1][2].z + eb*F[1][2].w
                       + ec*F[1][3].x + ed*F[1][3].y + ee*F[1][3].z + ef*F[1][3].w;
            }
            // halving reduce over sub bits: 8 h-partials -> 1 full pre per lane
            #pragma unroll
            for (int i = 0; i < 4; ++i) {
                float k0 = (sub & 1) ? hp0[i + 4] : hp0[i];
                float s0 = (sub & 1) ? hp0[i]     : hp0[i + 4];
                hp0[i] = k0 + __shfl_xor(s0, 1);
                float k1 = (sub & 1) ? hp1[i + 4] : hp1[i];
                float s1 = (sub & 1) ? hp1[i]     : hp1[i + 4];
                hp1[i] = k1 + __shfl_xor(s1, 1);
            }
            #pragma unroll
            for (int i = 0; i < 2; ++i) {
                float k0 = (sub & 2) ? hp0[i + 2] : hp0[i];
                float s0 = (sub & 2) ? hp0[i]     : hp0[i + 2];
                hp0[i] = k0 + __shfl_xor(s0, 2);
                float k1 = (sub & 2) ? hp1[i + 2] : hp1[i];
                float s1 = (sub & 2) ? hp1[i]     : hp1[i + 2];
                hp1[i] = k1 + __shfl_xor(s1, 2);
            }
            {
                float k0 = (sub & 4) ? hp0[1] : hp0[0];
                float s0 = (sub & 4) ? hp0[0] : hp0[1];
                hp0[0] = k0 + __shfl_xor(s0, 4);
                float k1 = (sub & 4) ? hp1[1] : hp1[0];
                float s1 = (sub & 4) ? hp1[0] : hp1[1];
                hp1[0] = k1 + __shfl_xor(s1, 4);
            }
            float qs = g ? qwB : qwA, ws = g ? w2B : w2A;
            sc0 += ws / (1.f + __expf(-(qs + hp0[0])));
            sc1 += ws / (1.f + __expf(-(qs + hp1[0])));
        }
        // full scores on all 8 sub lanes
        sc0 += __shfl_xor(sc0, 1); sc0 += __shfl_xor(sc0, 2); sc0 += __shfl_xor(sc0, 4);
        sc1 += __shfl_xor(sc1, 1); sc1 += __shfl_xor(sc1, 2); sc1 += __shfl_xor(sc1, 4);
        float s0 = mv[0] ? sc0 : -1e30f;
        float s1 = mv[1] ? sc1 : -1e30f;
        // online softmax across the wave's 16 rows
        float mt = fmaxf(s0, s1);
        mt = fmaxf(mt, __shfl_xor(mt, 8));
        mt = fmaxf(mt, __shfl_xor(mt, 16));
        mt = fmaxf(mt, __shfl_xor(mt, 32));
        float nm = fmaxf(m, mt);
        float w0 = mv[0] ? __expf(s0 - nm) : 0.f;
        float w1 = mv[1] ? __expf(s1 - nm) : 0.f;
        float ls = w0 + w1;
        ls += __shfl_xor(ls, 8); ls += __shfl_xor(ls, 16); ls += __shfl_xor(ls, 32);
        float fac = __expf(m - nm);        // first chunk: exp(-inf) = 0
        m = nm; l = l * fac + ls;
        #pragma unroll
        for (int k = 0; k < 4; ++k) {
            acc4[k].x = acc4[k].x * fac + w0 * F[0][k].x + w1 * F[1][k].x;
            acc4[k].y = acc4[k].y * fac + w0 * F[0][k].y + w1 * F[1][k].y;
            acc4[k].z = acc4[k].z * fac + w0 * F[0][k].z + w1 * F[1][k].z;
            acc4[k].w = acc4[k].w * fac + w0 * F[0][k].w + w1 * F[1][k].w;
        }
    };

    // ---- main loop: register double-buffer, static A/B ping-pong ----
    #pragma unroll 1
    for (int c = 0; c < NCH; c += 2) {
        if (c + 1 < NCH) loadFR(c + 1, FB, mvB);
        process(FA, mvA);
        if (c + 1 < NCH) {
            if (c + 2 < NCH) loadFR(c + 2, FA, mvA);
            process(FB, mvB);
        }
    }

    // ---- epilogue: halving-reduce acc over the 8 rowgroups, direct store ----
    float a[16];
    #pragma unroll
    for (int k = 0; k < 4; ++k) {
        a[4*k+0] = acc4[k].x; a[4*k+1] = acc4[k].y;
        a[4*k+2] = acc4[k].z; a[4*k+3] = acc4[k].w;
    }
    #pragma unroll
    for (int i = 0; i < 8; ++i) {
        float kp = (rg & 1) ? a[i + 8] : a[i];
        float sd = (rg & 1) ? a[i]     : a[i + 8];
        a[i] = kp + __shfl_xor(sd, 8);
    }
    #pragma unroll
    for (int i = 0; i < 4; ++i) {
        float kp = (rg & 2) ? a[i + 4] : a[i];
        float sd = (rg & 2) ? a[i]     : a[i + 4];
        a[i] = kp + __shfl_xor(sd, 16);
    }
    #pragma unroll
    for (int i = 0; i < 2; ++i) {
        float kp = (rg & 4) ? a[i + 2] : a[i];
        float sd = (rg & 4) ? a[i]     : a[i + 2];
        a[i] = kp + __shfl_xor(sd, 32);
    }
    int dl = sub * 16 + 8 * (rg & 1) + 4 * ((rg >> 1) & 1) + 2 * ((rg >> 2) & 1);
    float inv = 1.f / l;
    *(float2*)(out + (size_t)b * D_DIM + dl) = make_float2(a[0] * inv, a[1] * inv);
}

extern "C" void kernel_launch(void* const* d_in, const int* in_sizes, int n_in,
                              void* d_out, int out_size, void* d_ws, size_t ws_size,
                              hipStream_t stream) {
    const float* query = (const float*)d_in[0];
    const float* facts = (const float*)d_in[1];
    const int*   mask  = (const int*)d_in[2];   // harness delivers bool as int32
    const float* W1    = (const float*)d_in[3];
    const float* b1    = (const float*)d_in[4];
    const float* W2    = (const float*)d_in[5];
    // d_in[6] = b2: dropped (softmax shift-invariant)
    float* out = (float*)d_out;
    (void)in_sizes; (void)n_in; (void)out_size; (void)d_ws; (void)ws_size;

    din_fused<<<dim3(B_DIM / 8), dim3(512), 0, stream>>>(
        query, facts, mask, W1, b1, W2, out);
}

// Round 11
// 258.584 us; speedup vs baseline: 1.4263x; 1.3445x over previous
//
#include <hip/hip_runtime.h>

#define B_DIM 4096
#define T_DIM 200
#define D_DIM 128
#define H_DIM 16
#define NCH   13    // chunks of 16 rows (13*16 = 208 >= 200)

__device__ __forceinline__ float bflo(unsigned int u){ return __uint_as_float(u << 16); }
__device__ __forceinline__ float bfhi(unsigned int u){ return __uint_as_float(u & 0xffff0000u); }
__device__ __forceinline__ unsigned int pk_bf16(float a, float b){
    unsigned int ua = __float_as_uint(a), ub = __float_as_uint(b);
    unsigned int ra = (ua + 0x7fffu + ((ua >> 16) & 1u)) >> 16;
    unsigned int rb = (ub + 0x7fffu + ((ub >> 16) & 1u)) & 0xffff0000u;
    return rb | ra;
}

extern "C" __global__ __launch_bounds__(512)
void din_fused(const float* __restrict__ query,
               const float* __restrict__ facts,
               const int* __restrict__ mask,
               const float* __restrict__ W1,
               const float* __restrict__ b1,
               const float* __restrict__ W2,
               float* __restrict__ out)
{
    const int tid  = threadIdx.x;
    const int wid  = tid >> 6;        // 0..7 : wave = one b
    const int lane = tid & 63;
    const int sub  = lane & 7;        // d-octant: owns d = sub*16 .. +15
    const int rg   = lane >> 3;       // rowgroup: rows c*16 + 2*rg, +1
    const int b    = blockIdx.x * 8 + wid;

    __shared__ float W1bc[H_DIM * D_DIM];        // (W1b - W1c)[h][d]
    __shared__ float W1dd[H_DIM * D_DIM];        // W1d[h][d]
    __shared__ float W1ac[H_DIM * D_DIM];        // (W1a + W1c)[h][d]
    __shared__ unsigned int weffp[8][H_DIM * 64];// per-wave bf16x2 weff [h][d/2]
    __shared__ float qwl[8][H_DIM];              // per-wave qw

    const float* fb = facts + (size_t)b * (T_DIM * D_DIM);
    const int*   mb = mask  + (size_t)b * T_DIM;
    const float* qb = query + (size_t)b * D_DIM;

    float4 F[2][4];
    int mv[2];
    auto loadFR = [&](int c) {
        int r0 = c * 16 + 2 * rg, r1 = r0 + 1;
        int r0c = r0 < T_DIM ? r0 : T_DIM - 1;
        int r1c = r1 < T_DIM ? r1 : T_DIM - 1;
        #pragma unroll
        for (int k = 0; k < 4; ++k) {
            F[0][k] = *(const float4*)(fb + r0c * D_DIM + sub * 16 + 4 * k);
            F[1][k] = *(const float4*)(fb + r1c * D_DIM + sub * 16 + 4 * k);
        }
        mv[0] = (r0 < T_DIM) ? mb[r0c] : 0;
        mv[1] = (r1 < T_DIM) ? mb[r1c] : 0;
    };
    loadFR(0);   // chunk-0 loads in flight across the whole prologue

    // ---- one-time W1 transpose into LDS (only block-wide barrier in the kernel) ----
    #pragma unroll
    for (int i = 0; i < 4; ++i) {
        int idx = tid * 4 + i;                    // 0..2047 = h*128 + d
        int h = idx >> 7, d = idx & 127;
        W1bc[idx] = W1[(128 + d) * H_DIM + h] - W1[(256 + d) * H_DIM + h];
        W1dd[idx] = W1[(384 + d) * H_DIM + h];
        W1ac[idx] = W1[d * H_DIM + h] + W1[(256 + d) * H_DIM + h];
    }
    __syncthreads();

    // ---- per-wave qw: lane = (h = lane&15, dgrp = lane>>4) ----
    {
        int h = lane & 15, dg = lane >> 4;
        float p = 0.f;
        #pragma unroll
        for (int k = 0; k < 8; ++k) {
            float4 a4 = *(const float4*)&W1ac[h * D_DIM + dg * 32 + 4 * k];
            float4 q4 = *(const float4*)(qb + dg * 32 + 4 * k);
            p += a4.x * q4.x + a4.y * q4.y + a4.z * q4.z + a4.w * q4.w;
        }
        p += __shfl_xor(p, 16);
        p += __shfl_xor(p, 32);
        if (lane < 16) qwl[wid][h] = p + b1[h];
    }
    // ---- per-wave weff build (bf16-packed): lane covers h=lane>>2, 16 uints ----
    {
        int h = lane >> 2, du0 = (lane & 3) * 16;
        #pragma unroll
        for (int t = 0; t < 4; ++t) {
            unsigned int pk[4];
            #pragma unroll
            for (int u = 0; u < 4; ++u) {
                int d = (du0 + t * 4 + u) * 2;
                float2 q2 = *(const float2*)(qb + d);
                float2 bc = *(const float2*)&W1bc[h * D_DIM + d];
                float2 dd = *(const float2*)&W1dd[h * D_DIM + d];
                pk[u] = pk_bf16(bc.x + q2.x * dd.x, bc.y + q2.y * dd.y);
            }
            *(uint4*)&weffp[wid][h * 64 + du0 + t * 4] = make_uint4(pk[0], pk[1], pk[2], pk[3]);
        }
    }
    // wave-private LDS RAW (same wave wrote it); drain before reads
    asm volatile("s_waitcnt lgkmcnt(0)" ::: "memory");

    // lane's h after halving-reduce: hg (+8 for pass 1)
    const int hg = 4 * (sub & 1) + 2 * ((sub >> 1) & 1) + ((sub >> 2) & 1);
    const float qwA = qwl[wid][hg],     w2A = W2[hg];
    const float qwB = qwl[wid][hg + 8], w2B = W2[hg + 8];
    const unsigned int* wp = &weffp[wid][0];

    float4 acc4[4];
    #pragma unroll
    for (int k = 0; k < 4; ++k) acc4[k] = make_float4(0.f, 0.f, 0.f, 0.f);
    float m = -3e38f, l = 0.f;

    // ---- flash chunk processor: zero barriers, all wave-local ----
    auto process = [&]() {
        float sc0 = 0.f, sc1 = 0.f;
        #pragma unroll
        for (int g = 0; g < 2; ++g) {
            float hp0[8], hp1[8];
            #pragma unroll
            for (int i = 0; i < 8; ++i) {
                uint4 u0 = *(const uint4*)&wp[(g * 8 + i) * 64 + sub * 8];
                uint4 u1 = *(const uint4*)&wp[(g * 8 + i) * 64 + sub * 8 + 4];
                float e0 = bflo(u0.x), e1 = bfhi(u0.x), e2 = bflo(u0.y), e3 = bfhi(u0.y);
                float e4 = bflo(u0.z), e5 = bfhi(u0.z), e6 = bflo(u0.w), e7 = bfhi(u0.w);
                float e8 = bflo(u1.x), e9 = bfhi(u1.x), ea = bflo(u1.y), eb = bfhi(u1.y);
                float ec = bflo(u1.z), ed = bfhi(u1.z), ee = bflo(u1.w), ef = bfhi(u1.w);
                hp0[i] = e0*F[0][0].x + e1*F[0][0].y + e2*F[0][0].z + e3*F[0][0].w
                       + e4*F[0][1].x + e5*F[0][1].y + e6*F[0][1].z + e7*F[0][1].w
                       + e8*F[0][2].x + e9*F[0][2].y + ea*F[0][2].z + eb*F[0][2].w
                       + ec*F[0][3].x + ed*F[0][3].y + ee*F[0][3].z + ef*F[0][3].w;
                hp1[i] = e0*F[1][0].x + e1*F[1][0].y + e2*F[1][0].z + e3*F[1][0].w
                       + e4*F[1][1].x + e5*F[1][1].y + e6*F[1][1].z + e7*F[1][1].w
                       + e8*F[1][2].x + e9*F[1][2].y + ea*F[1][2].z + eb*F[1][2].w
                       + ec*F[1][3].x + ed*F[1][3].y + ee*F[1][3].z + ef*F[1][3].w;
            }
            // halving reduce over sub bits: 8 h-partials -> 1 full pre per lane
            #pragma unroll
            for (int i = 0; i < 4; ++i) {
                float k0 = (sub & 1) ? hp0[i + 4] : hp0[i];
                float s0 = (sub & 1) ? hp0[i]     : hp0[i + 4];
                hp0[i] = k0 + __shfl_xor(s0, 1);
                float k1 = (sub & 1) ? hp1[i + 4] : hp1[i];
                float s1 = (sub & 1) ? hp1[i]     : hp1[i + 4];
                hp1[i] = k1 + __shfl_xor(s1, 1);
            }
            #pragma unroll
            for (int i = 0; i < 2; ++i) {
                float k0 = (sub & 2) ? hp0[i + 2] : hp0[i];
                float s0 = (sub & 2) ? hp0[i]     : hp0[i + 2];
                hp0[i] = k0 + __shfl_xor(s0, 2);
                float k1 = (sub & 2) ? hp1[i + 2] : hp1[i];
                float s1 = (sub & 2) ? hp1[i]     : hp1[i + 2];
                hp1[i] = k1 + __shfl_xor(s1, 2);
            }
            {
                float k0 = (sub & 4) ? hp0[1] : hp0[0];
                float s0 = (sub & 4) ? hp0[0] : hp0[1];
                hp0[0] = k0 + __shfl_xor(s0, 4);
                float k1 = (sub & 4) ? hp1[1] : hp1[0];
                float s1 = (sub & 4) ? hp1[0] : hp1[1];
                hp1[0] = k1 + __shfl_xor(s1, 4);
            }
            float qs = g ? qwB : qwA, ws = g ? w2B : w2A;
            sc0 += ws / (1.f + __expf(-(qs + hp0[0])));
            sc1 += ws / (1.f + __expf(-(qs + hp1[0])));
        }
        // full scores on all 8 sub lanes
        sc0 += __shfl_xor(sc0, 1); sc0 += __shfl_xor(sc0, 2); sc0 += __shfl_xor(sc0, 4);
        sc1 += __shfl_xor(sc1, 1); sc1 += __shfl_xor(sc1, 2); sc1 += __shfl_xor(sc1, 4);
        float s0 = mv[0] ? sc0 : -1e30f;
        float s1 = mv[1] ? sc1 : -1e30f;
        // online softmax across the wave's 16 rows
        float mt = fmaxf(s0, s1);
        mt = fmaxf(mt, __shfl_xor(mt, 8));
        mt = fmaxf(mt, __shfl_xor(mt, 16));
        mt = fmaxf(mt, __shfl_xor(mt, 32));
        float nm = fmaxf(m, mt);
        float w0 = mv[0] ? __expf(s0 - nm) : 0.f;
        float w1 = mv[1] ? __expf(s1 - nm) : 0.f;
        float ls = w0 + w1;
        ls += __shfl_xor(ls, 8); ls += __shfl_xor(ls, 16); ls += __shfl_xor(ls, 32);
        float fac = __expf(m - nm);        // first chunk: exp(-inf) = 0
        m = nm; l = l * fac + ls;
        #pragma unroll
        for (int k = 0; k < 4; ++k) {
            acc4[k].x = acc4[k].x * fac + w0 * F[0][k].x + w1 * F[1][k].x;
            acc4[k].y = acc4[k].y * fac + w0 * F[0][k].y + w1 * F[1][k].y;
            acc4[k].z = acc4[k].z * fac + w0 * F[0][k].z + w1 * F[1][k].z;
            acc4[k].w = acc4[k].w * fac + w0 * F[0][k].w + w1 * F[1][k].w;
        }
    };

    // ---- main loop: single register buffer; TLP (4 waves/SIMD) hides the load latency ----
    process();                         // chunk 0 (loaded before prologue)
    #pragma unroll 1
    for (int c = 1; c < NCH; ++c) {
        loadFR(c);
        process();
    }

    // ---- epilogue: halving-reduce acc over the 8 rowgroups, direct store ----
    float a[16];
    #pragma unroll
    for (int k = 0; k < 4; ++k) {
        a[4*k+0] = acc4[k].x; a[4*k+1] = acc4[k].y;
        a[4*k+2] = acc4[k].z; a[4*k+3] = acc4[k].w;
    }
    #pragma unroll
    for (int i = 0; i < 8; ++i) {
        float kp = (rg & 1) ? a[i + 8] : a[i];
        float sd = (rg & 1) ? a[i]     : a[i + 8];
        a[i] = kp + __shfl_xor(sd, 8);
    }
    #pragma unroll
    for (int i = 0; i < 4; ++i) {
        float kp = (rg & 2) ? a[i + 4] : a[i];
        float sd = (rg & 2) ? a[i]     : a[i + 4];
        a[i] = kp + __shfl_xor(sd, 16);
    }
    #pragma unroll
    for (int i = 0; i < 2; ++i) {
        float kp = (rg & 4) ? a[i + 2] : a[i];
        float sd = (rg & 4) ? a[i]     : a[i + 2];
        a[i] = kp + __shfl_xor(sd, 32);
    }
    int dl = sub * 16 + 8 * (rg & 1) + 4 * ((rg >> 1) & 1) + 2 * ((rg >> 2) & 1);
    float inv = 1.f / l;
    *(float2*)(out + (size_t)b * D_DIM + dl) = make_float2(a[0] * inv, a[1] * inv);
}

extern "C" void kernel_launch(void* const* d_in, const int* in_sizes, int n_in,
                              void* d_out, int out_size, void* d_ws, size_t ws_size,
                              hipStream_t stream) {
    const float* query = (const float*)d_in[0];
    const float* facts = (const float*)d_in[1];
    const int*   mask  = (const int*)d_in[2];   // harness delivers bool as int32
    const float* W1    = (const float*)d_in[3];
    const float* b1    = (const float*)d_in[4];
    const float* W2    = (const float*)d_in[5];
    // d_in[6] = b2: dropped (softmax shift-invariant)
    float* out = (float*)d_out;
    (void)in_sizes; (void)n_in; (void)out_size; (void)d_ws; (void)ws_size;

    din_fused<<<dim3(B_DIM / 8), dim3(512), 0, stream>>>(
        query, facts, mask, W1, b1, W2, out);
}

// Round 12
// 145.869 us; speedup vs baseline: 2.5284x; 1.7727x over previous
//
#include <hip/hip_runtime.h>

#define B_DIM 4096
#define T_DIM 200
#define D_DIM 128
#define H_DIM 16
#define NCH   25    // chunks of 8 rows: 25*8 = 200 exactly, no tail logic

__device__ __forceinline__ float bflo(unsigned int u){ return __uint_as_float(u << 16); }
__device__ __forceinline__ float bfhi(unsigned int u){ return __uint_as_float(u & 0xffff0000u); }
__device__ __forceinline__ unsigned int pk_bf16(float a, float b){
    unsigned int ua = __float_as_uint(a), ub = __float_as_uint(b);
    unsigned int ra = (ua + 0x7fffu + ((ua >> 16) & 1u)) >> 16;
    unsigned int rb = (ub + 0x7fffu + ((ub >> 16) & 1u)) & 0xffff0000u;
    return rb | ra;
}

extern "C" __global__ __launch_bounds__(512)
void din_fused(const float* __restrict__ query,
               const float* __restrict__ facts,
               const int* __restrict__ mask,
               const float* __restrict__ W1,
               const float* __restrict__ b1,
               const float* __restrict__ W2,
               float* __restrict__ out)
{
    const int tid  = threadIdx.x;
    const int wid  = tid >> 6;        // 0..7 : wave = one b
    const int lane = tid & 63;
    const int sub  = lane & 15;       // d-octet: owns d = sub*8 .. +7
    const int rg   = lane >> 4;       // rowgroup (0..3): rows c*8 + 2*rg, +1
    const int b    = blockIdx.x * 8 + wid;

    __shared__ float W1bc[H_DIM * D_DIM];        // (W1b - W1c)[h][d]
    __shared__ float W1dd[H_DIM * D_DIM];        // W1d[h][d]
    __shared__ float W1ac[H_DIM * D_DIM];        // (W1a + W1c)[h][d]
    __shared__ unsigned int weffp[8][H_DIM * 64];// per-wave bf16x2 weff [h][d/2]
    __shared__ float qwl[8][H_DIM];              // per-wave qw

    const float* fb = facts + (size_t)b * (T_DIM * D_DIM);
    const int*   mb = mask  + (size_t)b * T_DIM;
    const float* qb = query + (size_t)b * D_DIM;

    float4 FA[2][2], FB[2][2];
    int mvA[2], mvB[2];
    auto loadFR = [&](int c, float4 (&F)[2][2], int (&mv)[2]) {
        int r0 = c * 8 + 2 * rg;                 // always < 200: no clamping
        #pragma unroll
        for (int k = 0; k < 2; ++k) {
            F[0][k] = *(const float4*)(fb + r0 * D_DIM       + sub * 8 + 4 * k);
            F[1][k] = *(const float4*)(fb + (r0+1) * D_DIM   + sub * 8 + 4 * k);
        }
        mv[0] = mb[r0];
        mv[1] = mb[r0 + 1];
    };
    loadFR(0, FA, mvA);   // chunk-0 loads in flight across the whole prologue

    // ---- one-time W1 transpose into LDS (only block-wide barrier in the kernel) ----
    #pragma unroll
    for (int i = 0; i < 4; ++i) {
        int idx = tid * 4 + i;                    // 0..2047 = h*128 + d
        int h = idx >> 7, d = idx & 127;
        W1bc[idx] = W1[(128 + d) * H_DIM + h] - W1[(256 + d) * H_DIM + h];
        W1dd[idx] = W1[(384 + d) * H_DIM + h];
        W1ac[idx] = W1[d * H_DIM + h] + W1[(256 + d) * H_DIM + h];
    }
    __syncthreads();

    // ---- per-wave qw: lane = (h = lane&15, dgrp = lane>>4) ----
    {
        int h = lane & 15, dg = lane >> 4;
        float p = 0.f;
        #pragma unroll
        for (int k = 0; k < 8; ++k) {
            float4 a4 = *(const float4*)&W1ac[h * D_DIM + dg * 32 + 4 * k];
            float4 q4 = *(const float4*)(qb + dg * 32 + 4 * k);
            p += a4.x * q4.x + a4.y * q4.y + a4.z * q4.z + a4.w * q4.w;
        }
        p += __shfl_xor(p, 16);
        p += __shfl_xor(p, 32);
        if (lane < 16) qwl[wid][h] = p + b1[h];
    }
    // ---- per-wave weff build (bf16-packed): lane covers h=lane>>2, 16 uints ----
    {
        int h = lane >> 2, du0 = (lane & 3) * 16;
        #pragma unroll
        for (int t = 0; t < 4; ++t) {
            unsigned int pk[4];
            #pragma unroll
            for (int u = 0; u < 4; ++u) {
                int d = (du0 + t * 4 + u) * 2;
                float2 q2 = *(const float2*)(qb + d);
                float2 bc = *(const float2*)&W1bc[h * D_DIM + d];
                float2 dd = *(const float2*)&W1dd[h * D_DIM + d];
                pk[u] = pk_bf16(bc.x + q2.x * dd.x, bc.y + q2.y * dd.y);
            }
            *(uint4*)&weffp[wid][h * 64 + du0 + t * 4] = make_uint4(pk[0], pk[1], pk[2], pk[3]);
        }
    }
    // wave-private LDS RAW (same wave wrote it); drain before reads
    asm volatile("s_waitcnt lgkmcnt(0)" ::: "memory");

    // lane's h after halving-reduce over sub bits 1,2,4 (bit 8 joins d-halves)
    const int hg = 4 * (sub & 1) + 2 * ((sub >> 1) & 1) + ((sub >> 2) & 1);
    const float qwA = qwl[wid][hg],     w2A = W2[hg];
    const float qwB = qwl[wid][hg + 8], w2B = W2[hg + 8];
    const unsigned int* wp = &weffp[wid][0];

    float4 acc[2];
    acc[0] = make_float4(0.f, 0.f, 0.f, 0.f);
    acc[1] = make_float4(0.f, 0.f, 0.f, 0.f);
    float m = -3e38f, l = 0.f;

    // ---- flash chunk processor: zero barriers, all wave-local ----
    auto process = [&](float4 (&F)[2][2], int (&mv)[2]) {
        float sc0 = 0.f, sc1 = 0.f;
        #pragma unroll
        for (int g = 0; g < 2; ++g) {
            float hp0[8], hp1[8];
            #pragma unroll
            for (int i = 0; i < 8; ++i) {
                uint4 u0 = *(const uint4*)&wp[(g * 8 + i) * 64 + sub * 4];
                float e0 = bflo(u0.x), e1 = bfhi(u0.x), e2 = bflo(u0.y), e3 = bfhi(u0.y);
                float e4 = bflo(u0.z), e5 = bfhi(u0.z), e6 = bflo(u0.w), e7 = bfhi(u0.w);
                hp0[i] = e0*F[0][0].x + e1*F[0][0].y + e2*F[0][0].z + e3*F[0][0].w
                       + e4*F[0][1].x + e5*F[0][1].y + e6*F[0][1].z + e7*F[0][1].w;
                hp1[i] = e0*F[1][0].x + e1*F[1][0].y + e2*F[1][0].z + e3*F[1][0].w
                       + e4*F[1][1].x + e5*F[1][1].y + e6*F[1][1].z + e7*F[1][1].w;
            }
            // halving reduce over sub bits 1,2,4; then bit 8 joins the two d-halves
            #pragma unroll
            for (int i = 0; i < 4; ++i) {
                float k0 = (sub & 1) ? hp0[i + 4] : hp0[i];
                float s0 = (sub & 1) ? hp0[i]     : hp0[i + 4];
                hp0[i] = k0 + __shfl_xor(s0, 1);
                float k1 = (sub & 1) ? hp1[i + 4] : hp1[i];
                float s1 = (sub & 1) ? hp1[i]     : hp1[i + 4];
                hp1[i] = k1 + __shfl_xor(s1, 1);
            }
            #pragma unroll
            for (int i = 0; i < 2; ++i) {
                float k0 = (sub & 2) ? hp0[i + 2] : hp0[i];
                float s0 = (sub & 2) ? hp0[i]     : hp0[i + 2];
                hp0[i] = k0 + __shfl_xor(s0, 2);
                float k1 = (sub & 2) ? hp1[i + 2] : hp1[i];
                float s1 = (sub & 2) ? hp1[i]     : hp1[i + 2];
                hp1[i] = k1 + __shfl_xor(s1, 2);
            }
            {
                float k0 = (sub & 4) ? hp0[1] : hp0[0];
                float s0 = (sub & 4) ? hp0[0] : hp0[1];
                hp0[0] = k0 + __shfl_xor(s0, 4);
                float k1 = (sub & 4) ? hp1[1] : hp1[0];
                float s1 = (sub & 4) ? hp1[0] : hp1[1];
                hp1[0] = k1 + __shfl_xor(s1, 4);
            }
            hp0[0] += __shfl_xor(hp0[0], 8);
            hp1[0] += __shfl_xor(hp1[0], 8);
            float qs = g ? qwB : qwA, ws = g ? w2B : w2A;
            sc0 += ws / (1.f + __expf(-(qs + hp0[0])));
            sc1 += ws / (1.f + __expf(-(qs + hp1[0])));
        }
        // full scores on all 16 sub lanes (bit-3 halves already identical)
        sc0 += __shfl_xor(sc0, 1); sc0 += __shfl_xor(sc0, 2); sc0 += __shfl_xor(sc0, 4);
        sc1 += __shfl_xor(sc1, 1); sc1 += __shfl_xor(sc1, 2); sc1 += __shfl_xor(sc1, 4);
        float s0 = mv[0] ? sc0 : -1e30f;
        float s1 = mv[1] ? sc1 : -1e30f;
        // online softmax across the wave's 8 rows (rg bits 16,32)
        float mt = fmaxf(s0, s1);
        mt = fmaxf(mt, __shfl_xor(mt, 16));
        mt = fmaxf(mt, __shfl_xor(mt, 32));
        float nm = fmaxf(m, mt);
        float w0 = mv[0] ? __expf(s0 - nm) : 0.f;
        float w1 = mv[1] ? __expf(s1 - nm) : 0.f;
        float ls = w0 + w1;
        ls += __shfl_xor(ls, 16); ls += __shfl_xor(ls, 32);
        float fac = __expf(m - nm);        // first chunk: exp(-inf) = 0
        m = nm; l = l * fac + ls;
        #pragma unroll
        for (int k = 0; k < 2; ++k) {
            acc[k].x = acc[k].x * fac + w0 * F[0][k].x + w1 * F[1][k].x;
            acc[k].y = acc[k].y * fac + w0 * F[0][k].y + w1 * F[1][k].y;
            acc[k].z = acc[k].z * fac + w0 * F[0][k].z + w1 * F[1][k].z;
            acc[k].w = acc[k].w * fac + w0 * F[0][k].w + w1 * F[1][k].w;
        }
    };

    // ---- main loop: register double-buffer, static A/B ping-pong ----
    #pragma unroll 1
    for (int c = 0; c < NCH - 1; c += 2) {     // c = 0,2,...,22
        loadFR(c + 1, FB, mvB);
        process(FA, mvA);
        loadFR(c + 2, FA, mvA);                // c+2 <= 24
        process(FB, mvB);
    }
    process(FA, mvA);                          // chunk 24

    // ---- epilogue: halving-reduce acc over the 4 rowgroups, direct store ----
    float a[8] = {acc[0].x, acc[0].y, acc[0].z, acc[0].w,
                  acc[1].x, acc[1].y, acc[1].z, acc[1].w};
    #pragma unroll
    for (int i = 0; i < 4; ++i) {
        float kp = (rg & 1) ? a[i + 4] : a[i];
        float sd = (rg & 1) ? a[i]     : a[i + 4];
        a[i] = kp + __shfl_xor(sd, 16);
    }
    #pragma unroll
    for (int i = 0; i < 2; ++i) {
        float kp = (rg & 2) ? a[i + 2] : a[i];
        float sd = (rg & 2) ? a[i]     : a[i + 2];
        a[i] = kp + __shfl_xor(sd, 32);
    }
    int dl = sub * 8 + 4 * (rg & 1) + 2 * ((rg >> 1) & 1);
    float inv = 1.f / l;
    *(float2*)(out + (size_t)b * D_DIM + dl) = make_float2(a[0] * inv, a[1] * inv);
}

extern "C" void kernel_launch(void* const* d_in, const int* in_sizes, int n_in,
                              void* d_out, int out_size, void* d_ws, size_t ws_size,
                              hipStream_t stream) {
    const float* query = (const float*)d_in[0];
    const float* facts = (const float*)d_in[1];
    const int*   mask  = (const int*)d_in[2];   // harness delivers bool as int32
    const float* W1    = (const float*)d_in[3];
    const float* b1    = (const float*)d_in[4];
    const float* W2    = (const float*)d_in[5];
    // d_in[6] = b2: dropped (softmax shift-invariant)
    float* out = (float*)d_out;
    (void)in_sizes; (void)n_in; (void)out_size; (void)d_ws; (void)ws_size;

    din_fused<<<dim3(B_DIM / 8), dim3(512), 0, stream>>>(
        query, facts, mask, W1, b1, W2, out);
}

// Round 14
// 124.340 us; speedup vs baseline: 2.9662x; 1.1731x over previous
//
#include <hip/hip_runtime.h>

#define B_DIM 4096
#define T_DIM 200
#define D_DIM 128
#define H_DIM 16
#define NCH   25    // chunks of 8 rows: 25*8 = 200 exactly

typedef _Float16 h2 __attribute__((ext_vector_type(2)));   // fdot2 operand type
typedef __fp16   g2 __attribute__((ext_vector_type(2)));   // cvt_pkrtz return type
union HU { unsigned int u; h2 h; };

__device__ __forceinline__ h2 pkh(float a, float b) {
    g2 t = __builtin_amdgcn_cvt_pkrtz(a, b);   // v_cvt_pkrtz_f16_f32
    return __builtin_bit_cast(h2, t);
}

extern "C" __global__ __launch_bounds__(512)
void din_fused(const float* __restrict__ query,
               const float* __restrict__ facts,
               const int* __restrict__ mask,
               const float* __restrict__ W1,
               const float* __restrict__ b1,
               const float* __restrict__ W2,
               float* __restrict__ out)
{
    const int tid  = threadIdx.x;
    const int wid  = tid >> 6;        // wave = one b
    const int lane = tid & 63;
    const int sub  = lane & 15;       // owns d = sub*8 .. +7
    const int rg   = lane >> 4;       // rows c*8 + 2*rg, +1
    const int b    = blockIdx.x * 8 + wid;

    __shared__ float W1bc[H_DIM * D_DIM];        // (W1b - W1c)[h][d]
    __shared__ float W1dd[H_DIM * D_DIM];        // W1d[h][d]
    __shared__ float W1ac[H_DIM * D_DIM];        // (W1a + W1c)[h][d]
    __shared__ unsigned int wef1[8][8 * 64];     // per-wave f16x2 weff, h=8..15 [h-8][dpair]
    __shared__ float qwl[8][H_DIM];

    const float* fb = facts + (size_t)b * (T_DIM * D_DIM);
    const int*   mb = mask  + (size_t)b * T_DIM;
    const float* qb = query + (size_t)b * D_DIM;

    float4 FA[2][2], FB[2][2];
    int mvA[2], mvB[2];
    auto loadF = [&](int c, float4 (&F)[2][2], int (&mv)[2]) {
        int r0 = c * 8 + 2 * rg;                 // always < 200
        #pragma unroll
        for (int k = 0; k < 2; ++k) {
            F[0][k] = *(const float4*)(fb + r0 * D_DIM     + sub * 8 + 4 * k);
            F[1][k] = *(const float4*)(fb + (r0+1) * D_DIM + sub * 8 + 4 * k);
        }
        mv[0] = mb[r0];
        mv[1] = mb[r0 + 1];
    };
    loadF(0, FA, mvA);   // chunk-0 loads fly across the whole prologue

    // ---- one-time W1 transpose (only block-wide barrier) ----
    #pragma unroll
    for (int i = 0; i < 4; ++i) {
        int idx = tid * 4 + i;                   // h*128 + d
        int h = idx >> 7, d = idx & 127;
        W1bc[idx] = W1[(128 + d) * H_DIM + h] - W1[(256 + d) * H_DIM + h];
        W1dd[idx] = W1[(384 + d) * H_DIM + h];
        W1ac[idx] = W1[d * H_DIM + h] + W1[(256 + d) * H_DIM + h];
    }
    __syncthreads();

    // ---- per-wave qw ----
    {
        int h = lane & 15, dg = lane >> 4;
        float p = 0.f;
        #pragma unroll
        for (int k = 0; k < 8; ++k) {
            float4 a4 = *(const float4*)&W1ac[h * D_DIM + dg * 32 + 4 * k];
            float4 q4 = *(const float4*)(qb + dg * 32 + 4 * k);
            p += a4.x * q4.x + a4.y * q4.y + a4.z * q4.z + a4.w * q4.w;
        }
        p += __shfl_xor(p, 16);
        p += __shfl_xor(p, 32);
        if (lane < 16) qwl[wid][h] = p + b1[h];
    }
    // ---- g=1 weff (h 8..15) -> per-wave LDS, f16x2 ----
    {
        int h  = 8 + (lane >> 3);
        int p0 = (lane & 7) * 8;                 // 8 d-pairs per lane
        unsigned int pk[8];
        #pragma unroll
        for (int u = 0; u < 8; ++u) {
            int d0 = 2 * (p0 + u);
            float a0 = W1bc[h * D_DIM + d0]     + qb[d0]     * W1dd[h * D_DIM + d0];
            float a1 = W1bc[h * D_DIM + d0 + 1] + qb[d0 + 1] * W1dd[h * D_DIM + d0 + 1];
            HU t; t.h = pkh(a0, a1); pk[u] = t.u;
        }
        *(uint4*)&wef1[wid][(h - 8) * 64 + p0]     = make_uint4(pk[0], pk[1], pk[2], pk[3]);
        *(uint4*)&wef1[wid][(h - 8) * 64 + p0 + 4] = make_uint4(pk[4], pk[5], pk[6], pk[7]);
    }
    // ---- g=0 weff (h 0..7) -> registers, f16x2 (32 VGPR) ----
    h2 wreg[8][4];
    {
        float qd[8];
        *(float4*)&qd[0] = *(const float4*)(qb + sub * 8);
        *(float4*)&qd[4] = *(const float4*)(qb + sub * 8 + 4);
        #pragma unroll
        for (int i = 0; i < 8; ++i) {
            #pragma unroll
            for (int j = 0; j < 4; ++j) {
                int d0 = sub * 8 + 2 * j;
                float a0 = W1bc[i * D_DIM + d0]     + qd[2*j]   * W1dd[i * D_DIM + d0];
                float a1 = W1bc[i * D_DIM + d0 + 1] + qd[2*j+1] * W1dd[i * D_DIM + d0 + 1];
                wreg[i][j] = pkh(a0, a1);
            }
        }
    }
    asm volatile("s_waitcnt lgkmcnt(0)" ::: "memory");

    // lane's h after halving-reduce over sub bits 1,2,4 (bit 8 joins d-halves)
    const int hg = 4 * (sub & 1) + 2 * ((sub >> 1) & 1) + ((sub >> 2) & 1);
    const float qwA = qwl[wid][hg],     w2A = W2[hg];
    const float qwB = qwl[wid][hg + 8], w2B = W2[hg + 8];
    const unsigned int* wp = &wef1[wid][0];

    float a8[8];
    #pragma unroll
    for (int i = 0; i < 8; ++i) a8[i] = 0.f;
    float lloc = 0.f;

    // ---- chunk processor: deferred softmax (scores bounded by sum|W2|), no rescale ----
    auto process = [&](float4 (&F)[2][2], int (&mv)[2]) {
        h2 H[2][4];                               // facts as f16 pairs; F dies here
        #pragma unroll
        for (int r = 0; r < 2; ++r) {
            H[r][0] = pkh(F[r][0].x, F[r][0].y);
            H[r][1] = pkh(F[r][0].z, F[r][0].w);
            H[r][2] = pkh(F[r][1].x, F[r][1].y);
            H[r][3] = pkh(F[r][1].z, F[r][1].w);
        }
        float sc0 = 0.f, sc1 = 0.f;
        #pragma unroll
        for (int g = 0; g < 2; ++g) {
            float hp0[8], hp1[8];
            #pragma unroll
            for (int i = 0; i < 8; ++i) {
                float t0 = 0.f, t1 = 0.f;
                if (g == 0) {
                    #pragma unroll
                    for (int j = 0; j < 4; ++j) {
                        t0 = __builtin_amdgcn_fdot2(wreg[i][j], H[0][j], t0, false);
                        t1 = __builtin_amdgcn_fdot2(wreg[i][j], H[1][j], t1, false);
                    }
                } else {
                    uint4 wl = *(const uint4*)&wp[i * 64 + sub * 4];
                    HU u0, u1, u2, u3;
                    u0.u = wl.x; u1.u = wl.y; u2.u = wl.z; u3.u = wl.w;
                    t0 = __builtin_amdgcn_fdot2(u0.h, H[0][0], t0, false);
                    t0 = __builtin_amdgcn_fdot2(u1.h, H[0][1], t0, false);
                    t0 = __builtin_amdgcn_fdot2(u2.h, H[0][2], t0, false);
                    t0 = __builtin_amdgcn_fdot2(u3.h, H[0][3], t0, false);
                    t1 = __builtin_amdgcn_fdot2(u0.h, H[1][0], t1, false);
                    t1 = __builtin_amdgcn_fdot2(u1.h, H[1][1], t1, false);
                    t1 = __builtin_amdgcn_fdot2(u2.h, H[1][2], t1, false);
                    t1 = __builtin_amdgcn_fdot2(u3.h, H[1][3], t1, false);
                }
                hp0[i] = t0; hp1[i] = t1;
            }
            // halving reduce over sub bits 1,2,4; bit 8 joins the two d-halves
            #pragma unroll
            for (int i = 0; i < 4; ++i) {
                float k0 = (sub & 1) ? hp0[i + 4] : hp0[i];
                float s0 = (sub & 1) ? hp0[i]     : hp0[i + 4];
                hp0[i] = k0 + __shfl_xor(s0, 1);
                float k1 = (sub & 1) ? hp1[i + 4] : hp1[i];
                float s1 = (sub & 1) ? hp1[i]     : hp1[i + 4];
                hp1[i] = k1 + __shfl_xor(s1, 1);
            }
            #pragma unroll
            for (int i = 0; i < 2; ++i) {
                float k0 = (sub & 2) ? hp0[i + 2] : hp0[i];
                float s0 = (sub & 2) ? hp0[i]     : hp0[i + 2];
                hp0[i] = k0 + __shfl_xor(s0, 2);
                float k1 = (sub & 2) ? hp1[i + 2] : hp1[i];
                float s1 = (sub & 2) ? hp1[i]     : hp1[i + 2];
                hp1[i] = k1 + __shfl_xor(s1, 2);
            }
            {
                float k0 = (sub & 4) ? hp0[1] : hp0[0];
                float s0 = (sub & 4) ? hp0[0] : hp0[1];
                hp0[0] = k0 + __shfl_xor(s0, 4);
                float k1 = (sub & 4) ? hp1[1] : hp1[0];
                float s1 = (sub & 4) ? hp1[0] : hp1[1];
                hp1[0] = k1 + __shfl_xor(s1, 4);
            }
            hp0[0] += __shfl_xor(hp0[0], 8);
            hp1[0] += __shfl_xor(hp1[0], 8);
            float qs = g ? qwB : qwA, ws = g ? w2B : w2A;
            sc0 += ws / (1.f + __expf(-(qs + hp0[0])));
            sc1 += ws / (1.f + __expf(-(qs + hp1[0])));
        }
        // broadcast full scores to all 16 sub lanes
        sc0 += __shfl_xor(sc0, 1); sc0 += __shfl_xor(sc0, 2); sc0 += __shfl_xor(sc0, 4);
        sc1 += __shfl_xor(sc1, 1); sc1 += __shfl_xor(sc1, 2); sc1 += __shfl_xor(sc1, 4);
        float w0 = mv[0] ? __expf(sc0) : 0.f;    // |sc| <= sum|W2|: no overflow possible
        float w1 = mv[1] ? __expf(sc1) : 0.f;
        lloc += w0 + w1;
        #pragma unroll
        for (int j = 0; j < 4; ++j) {
            a8[2*j]     += w0 * (float)H[0][j].x + w1 * (float)H[1][j].x;
            a8[2*j + 1] += w0 * (float)H[0][j].y + w1 * (float)H[1][j].y;
        }
    };

    // ---- main loop: register double-buffer ping-pong ----
    #pragma unroll 1
    for (int c = 0; c < NCH - 1; c += 2) {
        loadF(c + 1, FB, mvB);
        process(FA, mvA);
        loadF(c + 2, FA, mvA);
        process(FB, mvB);
    }
    process(FA, mvA);                             // chunk 24

    // ---- epilogue: reduce l over rowgroups; halving-reduce a8; store ----
    float l = lloc;
    l += __shfl_xor(l, 16);
    l += __shfl_xor(l, 32);
    #pragma unroll
    for (int i = 0; i < 4; ++i) {
        float kp = (rg & 1) ? a8[i + 4] : a8[i];
        float sd = (rg & 1) ? a8[i]     : a8[i + 4];
        a8[i] = kp + __shfl_xor(sd, 16);
    }
    #pragma unroll
    for (int i = 0; i < 2; ++i) {
        float kp = (rg & 2) ? a8[i + 2] : a8[i];
        float sd = (rg & 2) ? a8[i]     : a8[i + 2];
        a8[i] = kp + __shfl_xor(sd, 32);
    }
    int dl = sub * 8 + 4 * (rg & 1) + 2 * ((rg >> 1) & 1);
    float inv = 1.f / l;
    *(float2*)(out + (size_t)b * D_DIM + dl) = make_float2(a8[0] * inv, a8[1] * inv);
}

extern "C" void kernel_launch(void* const* d_in, const int* in_sizes, int n_in,
                              void* d_out, int out_size, void* d_ws, size_t ws_size,
                              hipStream_t stream) {
    const float* query = (const float*)d_in[0];
    const float* facts = (const float*)d_in[1];
    const int*   mask  = (const int*)d_in[2];   // harness delivers bool as int32
    const float* W1    = (const float*)d_in[3];
    const float* b1    = (const float*)d_in[4];
    const float* W2    = (const float*)d_in[5];
    // d_in[6] = b2: dropped (cancels in softmax ratio)
    float* out = (float*)d_out;
    (void)in_sizes; (void)n_in; (void)out_size; (void)d_ws; (void)ws_size;

    din_fused<<<dim3(B_DIM / 8), dim3(512), 0, stream>>>(
        query, facts, mask, W1, b1, W2, out);
}

// Round 15
// 110.817 us; speedup vs baseline: 3.3281x; 1.1220x over previous
//
#include <hip/hip_runtime.h>

#define B_DIM 4096
#define T_DIM 200
#define D_DIM 128
#define H_DIM 16
#define NCH   25    // chunks of 8 rows: 25*8 = 200 exactly

typedef _Float16 h2 __attribute__((ext_vector_type(2)));   // fdot2 operand type
typedef __fp16   g2 __attribute__((ext_vector_type(2)));   // cvt_pkrtz return type
union HU { unsigned int u; h2 h; };

__device__ __forceinline__ h2 pkh(float a, float b) {
    g2 t = __builtin_amdgcn_cvt_pkrtz(a, b);   // v_cvt_pkrtz_f16_f32
    return __builtin_bit_cast(h2, t);
}

// VALU-pipe cross-lane move (v_mov_dpp). 0xB1=quad_perm xor1, 0x4E=quad_perm xor2,
// 0x128=row_ror:8 == xor8 within each 16-lane row.
template<int CTRL>
__device__ __forceinline__ float dppmov(float x) {
    return __builtin_bit_cast(float,
        __builtin_amdgcn_update_dpp(0, __builtin_bit_cast(int, x), CTRL, 0xF, 0xF, true));
}
// DS-pipe lane xor-4 (the one bit DPP can't do): BitMode offset (4<<10)|0x1F
__device__ __forceinline__ float swz4f(float x) {
    return __builtin_bit_cast(float,
        __builtin_amdgcn_ds_swizzle(__builtin_bit_cast(int, x), 0x101F));
}

extern "C" __global__ __launch_bounds__(512)
void din_fused(const float* __restrict__ query,
               const float* __restrict__ facts,
               const int* __restrict__ mask,
               const float* __restrict__ W1,
               const float* __restrict__ b1,
               const float* __restrict__ W2,
               float* __restrict__ out)
{
    const int tid  = threadIdx.x;
    const int wid  = tid >> 6;        // wave = one b
    const int lane = tid & 63;
    const int sub  = lane & 15;       // owns d = sub*8 .. +7
    const int rg   = lane >> 4;       // rows c*8 + 2*rg, +1
    const int b    = blockIdx.x * 8 + wid;

    __shared__ float W1bc[H_DIM * D_DIM];        // (W1b - W1c)[h][d]
    __shared__ float W1dd[H_DIM * D_DIM];        // W1d[h][d]
    __shared__ float W1ac[H_DIM * D_DIM];        // (W1a + W1c)[h][d]
    __shared__ unsigned int wef1[8][8 * 64];     // per-wave f16x2 weff, h=8..15
    __shared__ float qwl[8][H_DIM];

    const float* fb = facts + (size_t)b * (T_DIM * D_DIM);
    const int*   mb = mask  + (size_t)b * T_DIM;
    const float* qb = query + (size_t)b * D_DIM;

    float4 FA[2][2], FB[2][2];
    int mvA[2], mvB[2];
    auto loadF = [&](int c, float4 (&F)[2][2], int (&mv)[2]) {
        int r0 = c * 8 + 2 * rg;                 // always < 200
        #pragma unroll
        for (int k = 0; k < 2; ++k) {
            F[0][k] = *(const float4*)(fb + r0 * D_DIM     + sub * 8 + 4 * k);
            F[1][k] = *(const float4*)(fb + (r0+1) * D_DIM + sub * 8 + 4 * k);
        }
        mv[0] = mb[r0];
        mv[1] = mb[r0 + 1];
    };
    loadF(0, FA, mvA);   // chunk-0 loads fly across the whole prologue

    // ---- one-time W1 transpose (only block-wide barrier) ----
    #pragma unroll
    for (int i = 0; i < 4; ++i) {
        int idx = tid * 4 + i;                   // h*128 + d
        int h = idx >> 7, d = idx & 127;
        W1bc[idx] = W1[(128 + d) * H_DIM + h] - W1[(256 + d) * H_DIM + h];
        W1dd[idx] = W1[(384 + d) * H_DIM + h];
        W1ac[idx] = W1[d * H_DIM + h] + W1[(256 + d) * H_DIM + h];
    }
    __syncthreads();

    // ---- per-wave qw ----
    {
        int h = lane & 15, dg = lane >> 4;
        float p = 0.f;
        #pragma unroll
        for (int k = 0; k < 8; ++k) {
            float4 a4 = *(const float4*)&W1ac[h * D_DIM + dg * 32 + 4 * k];
            float4 q4 = *(const float4*)(qb + dg * 32 + 4 * k);
            p += a4.x * q4.x + a4.y * q4.y + a4.z * q4.z + a4.w * q4.w;
        }
        p += __shfl_xor(p, 16);
        p += __shfl_xor(p, 32);
        if (lane < 16) qwl[wid][h] = p + b1[h];
    }
    // ---- g=1 weff (h 8..15) -> per-wave LDS, f16x2 ----
    {
        int h  = 8 + (lane >> 3);
        int p0 = (lane & 7) * 8;                 // 8 d-pairs per lane
        unsigned int pk[8];
        #pragma unroll
        for (int u = 0; u < 8; ++u) {
            int d0 = 2 * (p0 + u);
            float a0 = W1bc[h * D_DIM + d0]     + qb[d0]     * W1dd[h * D_DIM + d0];
            float a1 = W1bc[h * D_DIM + d0 + 1] + qb[d0 + 1] * W1dd[h * D_DIM + d0 + 1];
            HU t; t.h = pkh(a0, a1); pk[u] = t.u;
        }
        *(uint4*)&wef1[wid][(h - 8) * 64 + p0]     = make_uint4(pk[0], pk[1], pk[2], pk[3]);
        *(uint4*)&wef1[wid][(h - 8) * 64 + p0 + 4] = make_uint4(pk[4], pk[5], pk[6], pk[7]);
    }
    // ---- g=0 weff (h 0..7) -> registers, f16x2 (32 VGPR) ----
    h2 wreg[8][4];
    {
        float qd[8];
        *(float4*)&qd[0] = *(const float4*)(qb + sub * 8);
        *(float4*)&qd[4] = *(const float4*)(qb + sub * 8 + 4);
        #pragma unroll
        for (int i = 0; i < 8; ++i) {
            #pragma unroll
            for (int j = 0; j < 4; ++j) {
                int d0 = sub * 8 + 2 * j;
                float a0 = W1bc[i * D_DIM + d0]     + qd[2*j]   * W1dd[i * D_DIM + d0];
                float a1 = W1bc[i * D_DIM + d0 + 1] + qd[2*j+1] * W1dd[i * D_DIM + d0 + 1];
                wreg[i][j] = pkh(a0, a1);
            }
        }
    }
    asm volatile("s_waitcnt lgkmcnt(0)" ::: "memory");

    // lane's h after DPP tree over bits {1,2,8}: h bit2=sub&1, bit1=sub&2, bit0=sub&8
    const int hg = 4 * (sub & 1) + 2 * ((sub >> 1) & 1) + ((sub >> 3) & 1);
    const float qwA = qwl[wid][hg],     w2A = W2[hg];
    const float qwB = qwl[wid][hg + 8], w2B = W2[hg + 8];
    const unsigned int* wp = &wef1[wid][0];

    float a8[8];
    #pragma unroll
    for (int i = 0; i < 8; ++i) a8[i] = 0.f;
    float lloc = 0.f;

    // ---- chunk processor: DPP tree (VALU pipe), 12 DS ops/chunk total ----
    auto process = [&](float4 (&F)[2][2], int (&mv)[2]) {
        h2 H[2][4];
        #pragma unroll
        for (int r = 0; r < 2; ++r) {
            H[r][0] = pkh(F[r][0].x, F[r][0].y);
            H[r][1] = pkh(F[r][0].z, F[r][0].w);
            H[r][2] = pkh(F[r][1].x, F[r][1].y);
            H[r][3] = pkh(F[r][1].z, F[r][1].w);
        }
        float sc0 = 0.f, sc1 = 0.f;
        #pragma unroll
        for (int g = 0; g < 2; ++g) {
            float hp0[8], hp1[8];
            #pragma unroll
            for (int i = 0; i < 8; ++i) {
                float t0 = 0.f, t1 = 0.f;
                if (g == 0) {
                    #pragma unroll
                    for (int j = 0; j < 4; ++j) {
                        t0 = __builtin_amdgcn_fdot2(wreg[i][j], H[0][j], t0, false);
                        t1 = __builtin_amdgcn_fdot2(wreg[i][j], H[1][j], t1, false);
                    }
                } else {
                    uint4 wl = *(const uint4*)&wp[i * 64 + sub * 4];
                    HU u0, u1, u2, u3;
                    u0.u = wl.x; u1.u = wl.y; u2.u = wl.z; u3.u = wl.w;
                    t0 = __builtin_amdgcn_fdot2(u0.h, H[0][0], t0, false);
                    t0 = __builtin_amdgcn_fdot2(u1.h, H[0][1], t0, false);
                    t0 = __builtin_amdgcn_fdot2(u2.h, H[0][2], t0, false);
                    t0 = __builtin_amdgcn_fdot2(u3.h, H[0][3], t0, false);
                    t1 = __builtin_amdgcn_fdot2(u0.h, H[1][0], t1, false);
                    t1 = __builtin_amdgcn_fdot2(u1.h, H[1][1], t1, false);
                    t1 = __builtin_amdgcn_fdot2(u2.h, H[1][2], t1, false);
                    t1 = __builtin_amdgcn_fdot2(u3.h, H[1][3], t1, false);
                }
                hp0[i] = t0; hp1[i] = t1;
            }
            // halving tree, level 1: lane bit 1 (quad_perm xor1, VALU)
            #pragma unroll
            for (int i = 0; i < 4; ++i) {
                float k0 = (sub & 1) ? hp0[i + 4] : hp0[i];
                float s0 = (sub & 1) ? hp0[i]     : hp0[i + 4];
                hp0[i] = k0 + dppmov<0xB1>(s0);
                float k1 = (sub & 1) ? hp1[i + 4] : hp1[i];
                float s1 = (sub & 1) ? hp1[i]     : hp1[i + 4];
                hp1[i] = k1 + dppmov<0xB1>(s1);
            }
            // level 2: lane bit 2 (quad_perm xor2, VALU)
            #pragma unroll
            for (int i = 0; i < 2; ++i) {
                float k0 = (sub & 2) ? hp0[i + 2] : hp0[i];
                float s0 = (sub & 2) ? hp0[i]     : hp0[i + 2];
                hp0[i] = k0 + dppmov<0x4E>(s0);
                float k1 = (sub & 2) ? hp1[i + 2] : hp1[i];
                float s1 = (sub & 2) ? hp1[i]     : hp1[i + 2];
                hp1[i] = k1 + dppmov<0x4E>(s1);
            }
            // level 3: lane bit 8 (row_ror:8 == xor8, VALU)
            {
                float k0 = (sub & 8) ? hp0[1] : hp0[0];
                float s0 = (sub & 8) ? hp0[0] : hp0[1];
                hp0[0] = k0 + dppmov<0x128>(s0);
                float k1 = (sub & 8) ? hp1[1] : hp1[0];
                float s1 = (sub & 8) ? hp1[0] : hp1[1];
                hp1[0] = k1 + dppmov<0x128>(s1);
            }
            // d-half join: lane bit 4 (ds_swizzle, the only DS op in the tree)
            hp0[0] += swz4f(hp0[0]);
            hp1[0] += swz4f(hp1[0]);
            float qs = g ? qwB : qwA, ws = g ? w2B : w2A;
            sc0 += ws / (1.f + __expf(-(qs + hp0[0])));
            sc1 += ws / (1.f + __expf(-(qs + hp1[0])));
        }
        // broadcast-sum the 8 per-lane h-contribs over bits {1,2,8} (all VALU DPP)
        sc0 += dppmov<0xB1>(sc0);
        sc0 += dppmov<0x4E>(sc0);
        sc0 += dppmov<0x128>(sc0);
        sc1 += dppmov<0xB1>(sc1);
        sc1 += dppmov<0x4E>(sc1);
        sc1 += dppmov<0x128>(sc1);
        float w0 = mv[0] ? __expf(sc0) : 0.f;    // deferred softmax: |sc| <= sum|W2|
        float w1 = mv[1] ? __expf(sc1) : 0.f;
        lloc += w0 + w1;
        #pragma unroll
        for (int j = 0; j < 4; ++j) {
            a8[2*j]     += w0 * (float)H[0][j].x + w1 * (float)H[1][j].x;
            a8[2*j + 1] += w0 * (float)H[0][j].y + w1 * (float)H[1][j].y;
        }
    };

    // ---- main loop: register double-buffer ping-pong ----
    #pragma unroll 1
    for (int c = 0; c < NCH - 1; c += 2) {
        loadF(c + 1, FB, mvB);
        process(FA, mvA);
        loadF(c + 2, FA, mvA);
        process(FB, mvB);
    }
    process(FA, mvA);                             // chunk 24

    // ---- epilogue: reduce l over rowgroups; halving-reduce a8; store ----
    float l = lloc;
    l += __shfl_xor(l, 16);
    l += __shfl_xor(l, 32);
    #pragma unroll
    for (int i = 0; i < 4; ++i) {
        float kp = (rg & 1) ? a8[i + 4] : a8[i];
        float sd = (rg & 1) ? a8[i]     : a8[i + 4];
        a8[i] = kp + __shfl_xor(sd, 16);
    }
    #pragma unroll
    for (int i = 0; i < 2; ++i) {
        float kp = (rg & 2) ? a8[i + 2] : a8[i];
        float sd = (rg & 2) ? a8[i]     : a8[i + 2];
        a8[i] = kp + __shfl_xor(sd, 32);
    }
    int dl = sub * 8 + 4 * (rg & 1) + 2 * ((rg >> 1) & 1);
    float inv = 1.f / l;
    *(float2*)(out + (size_t)b * D_DIM + dl) = make_float2(a8[0] * inv, a8[1] * inv);
}

extern "C" void kernel_launch(void* const* d_in, const int* in_sizes, int n_in,
                              void* d_out, int out_size, void* d_ws, size_t ws_size,
                              hipStream_t stream) {
    const float* query = (const float*)d_in[0];
    const float* facts = (const float*)d_in[1];
    const int*   mask  = (const int*)d_in[2];   // harness delivers bool as int32
    const float* W1    = (const float*)d_in[3];
    const float* b1    = (const float*)d_in[4];
    const float* W2    = (const float*)d_in[5];
    // d_in[6] = b2: dropped (cancels in softmax ratio)
    float* out = (float*)d_out;
    (void)in_sizes; (void)n_in; (void)out_size; (void)d_ws; (void)ws_size;

    din_fused<<<dim3(B_DIM / 8), dim3(512), 0, stream>>>(
        query, facts, mask, W1, b1, W2, out);
}

// Round 16
// 101.995 us; speedup vs baseline: 3.6160x; 1.0865x over previous
//
#include <hip/hip_runtime.h>

#define B_DIM 4096
#define T_DIM 200
#define D_DIM 128
#define H_DIM 16
#define NCH   25    // chunks of 8 rows: 25*8 = 200 exactly

typedef _Float16 h2 __attribute__((ext_vector_type(2)));   // fdot2 operand type
typedef __fp16   g2 __attribute__((ext_vector_type(2)));   // cvt_pkrtz return type
union HU { unsigned int u; h2 h; };

__device__ __forceinline__ h2 pkh(float a, float b) {
    g2 t = __builtin_amdgcn_cvt_pkrtz(a, b);   // v_cvt_pkrtz_f16_f32
    return __builtin_bit_cast(h2, t);
}

// VALU-pipe cross-lane move (v_mov_dpp). 0xB1=quad_perm xor1, 0x4E=quad_perm xor2,
// 0x128=row_ror:8 == xor8 within each 16-lane row.
template<int CTRL>
__device__ __forceinline__ float dppmov(float x) {
    return __builtin_bit_cast(float,
        __builtin_amdgcn_update_dpp(0, __builtin_bit_cast(int, x), CTRL, 0xF, 0xF, true));
}
// DS-pipe lane xor-4: BitMode offset (4<<10)|0x1F
__device__ __forceinline__ float swz4f(float x) {
    return __builtin_bit_cast(float,
        __builtin_amdgcn_ds_swizzle(__builtin_bit_cast(int, x), 0x101F));
}

extern "C" __global__ __launch_bounds__(512)
void din_fused(const float* __restrict__ query,
               const float* __restrict__ facts,
               const int* __restrict__ mask,
               const float* __restrict__ W1,
               const float* __restrict__ b1,
               const float* __restrict__ W2,
               float* __restrict__ out)
{
    const int tid  = threadIdx.x;
    const int wid  = tid >> 6;        // wave = one b
    const int lane = tid & 63;
    const int sub  = lane & 15;       // owns d = sub*8 .. +7
    const int rg   = lane >> 4;       // rows c*8 + 2*rg, +1
    const int b    = blockIdx.x * 8 + wid;

    __shared__ float W1bc[H_DIM * D_DIM];        // (W1b - W1c)[h][d]
    __shared__ float W1dd[H_DIM * D_DIM];        // W1d[h][d]
    __shared__ float W1ac[H_DIM * D_DIM];        // (W1a + W1c)[h][d]
    __shared__ unsigned int wef[8][H_DIM * 64];  // per-wave f16x2 weff, ALL 16 h
    __shared__ float qwl[8][H_DIM];

    const float* fb = facts + (size_t)b * (T_DIM * D_DIM);
    const int*   mb = mask  + (size_t)b * T_DIM;
    const float* qb = query + (size_t)b * D_DIM;

    float4 FA[2][2], FB[2][2], FC[2][2];         // 3-deep rotating prefetch
    int mvA[2], mvB[2], mvC[2];
    auto loadF = [&](int c, float4 (&F)[2][2], int (&mv)[2]) {
        int r0 = c * 8 + 2 * rg;                 // always < 200
        #pragma unroll
        for (int k = 0; k < 2; ++k) {
            F[0][k] = *(const float4*)(fb + r0 * D_DIM     + sub * 8 + 4 * k);
            F[1][k] = *(const float4*)(fb + (r0+1) * D_DIM + sub * 8 + 4 * k);
        }
        mv[0] = mb[r0];
        mv[1] = mb[r0 + 1];
    };
    loadF(0, FA, mvA);   // chunks 0,1 fly across the whole prologue
    loadF(1, FB, mvB);

    // ---- one-time W1 transpose (only block-wide barrier) ----
    #pragma unroll
    for (int i = 0; i < 4; ++i) {
        int idx = tid * 4 + i;                   // h*128 + d
        int h = idx >> 7, d = idx & 127;
        W1bc[idx] = W1[(128 + d) * H_DIM + h] - W1[(256 + d) * H_DIM + h];
        W1dd[idx] = W1[(384 + d) * H_DIM + h];
        W1ac[idx] = W1[d * H_DIM + h] + W1[(256 + d) * H_DIM + h];
    }
    __syncthreads();

    // ---- per-wave qw ----
    {
        int h = lane & 15, dg = lane >> 4;
        float p = 0.f;
        #pragma unroll
        for (int k = 0; k < 8; ++k) {
            float4 a4 = *(const float4*)&W1ac[h * D_DIM + dg * 32 + 4 * k];
            float4 q4 = *(const float4*)(qb + dg * 32 + 4 * k);
            p += a4.x * q4.x + a4.y * q4.y + a4.z * q4.z + a4.w * q4.w;
        }
        p += __shfl_xor(p, 16);
        p += __shfl_xor(p, 32);
        if (lane < 16) qwl[wid][h] = p + b1[h];
    }
    // ---- weff (ALL 16 h) -> per-wave LDS, f16x2; two 8-h passes ----
    #pragma unroll
    for (int pass = 0; pass < 2; ++pass) {
        int h  = 8 * pass + (lane >> 3);
        int p0 = (lane & 7) * 8;                 // 8 d-pairs per lane
        unsigned int pk[8];
        #pragma unroll
        for (int u = 0; u < 8; ++u) {
            int d0 = 2 * (p0 + u);
            float a0 = W1bc[h * D_DIM + d0]     + qb[d0]     * W1dd[h * D_DIM + d0];
            float a1 = W1bc[h * D_DIM + d0 + 1] + qb[d0 + 1] * W1dd[h * D_DIM + d0 + 1];
            HU t; t.h = pkh(a0, a1); pk[u] = t.u;
        }
        *(uint4*)&wef[wid][h * 64 + p0]     = make_uint4(pk[0], pk[1], pk[2], pk[3]);
        *(uint4*)&wef[wid][h * 64 + p0 + 4] = make_uint4(pk[4], pk[5], pk[6], pk[7]);
    }
    asm volatile("s_waitcnt lgkmcnt(0)" ::: "memory");   // wave-private LDS RAW

    // lane's h after DPP tree over bits {1,2,8}
    const int hg = 4 * (sub & 1) + 2 * ((sub >> 1) & 1) + ((sub >> 3) & 1);
    const float qwA = qwl[wid][hg],     w2A = W2[hg];
    const float qwB = qwl[wid][hg + 8], w2B = W2[hg + 8];
    const unsigned int* wp = &wef[wid][0];

    float a8[8];
    #pragma unroll
    for (int i = 0; i < 8; ++i) a8[i] = 0.f;
    float lloc = 0.f;

    // ---- chunk processor: fdot2 scoring, DPP tree, deferred softmax ----
    auto process = [&](float4 (&F)[2][2], int (&mv)[2]) {
        h2 H[2][4];
        #pragma unroll
        for (int r = 0; r < 2; ++r) {
            H[r][0] = pkh(F[r][0].x, F[r][0].y);
            H[r][1] = pkh(F[r][0].z, F[r][0].w);
            H[r][2] = pkh(F[r][1].x, F[r][1].y);
            H[r][3] = pkh(F[r][1].z, F[r][1].w);
        }
        float sc0 = 0.f, sc1 = 0.f;
        #pragma unroll
        for (int g = 0; g < 2; ++g) {
            float hp0[8], hp1[8];
            #pragma unroll
            for (int i = 0; i < 8; ++i) {
                uint4 wl = *(const uint4*)&wp[(g * 8 + i) * 64 + sub * 4];
                HU u0, u1, u2, u3;
                u0.u = wl.x; u1.u = wl.y; u2.u = wl.z; u3.u = wl.w;
                float t0 = 0.f, t1 = 0.f;
                t0 = __builtin_amdgcn_fdot2(u0.h, H[0][0], t0, false);
                t0 = __builtin_amdgcn_fdot2(u1.h, H[0][1], t0, false);
                t0 = __builtin_amdgcn_fdot2(u2.h, H[0][2], t0, false);
                t0 = __builtin_amdgcn_fdot2(u3.h, H[0][3], t0, false);
                t1 = __builtin_amdgcn_fdot2(u0.h, H[1][0], t1, false);
                t1 = __builtin_amdgcn_fdot2(u1.h, H[1][1], t1, false);
                t1 = __builtin_amdgcn_fdot2(u2.h, H[1][2], t1, false);
                t1 = __builtin_amdgcn_fdot2(u3.h, H[1][3], t1, false);
                hp0[i] = t0; hp1[i] = t1;
            }
            // halving tree: bits 1, 2 (quad_perm), 8 (row_ror:8) — all VALU
            #pragma unroll
            for (int i = 0; i < 4; ++i) {
                float k0 = (sub & 1) ? hp0[i + 4] : hp0[i];
                float s0 = (sub & 1) ? hp0[i]     : hp0[i + 4];
                hp0[i] = k0 + dppmov<0xB1>(s0);
                float k1 = (sub & 1) ? hp1[i + 4] : hp1[i];
                float s1 = (sub & 1) ? hp1[i]     : hp1[i + 4];
                hp1[i] = k1 + dppmov<0xB1>(s1);
            }
            #pragma unroll
            for (int i = 0; i < 2; ++i) {
                float k0 = (sub & 2) ? hp0[i + 2] : hp0[i];
                float s0 = (sub & 2) ? hp0[i]     : hp0[i + 2];
                hp0[i] = k0 + dppmov<0x4E>(s0);
                float k1 = (sub & 2) ? hp1[i + 2] : hp1[i];
                float s1 = (sub & 2) ? hp1[i]     : hp1[i + 2];
                hp1[i] = k1 + dppmov<0x4E>(s1);
            }
            {
                float k0 = (sub & 8) ? hp0[1] : hp0[0];
                float s0 = (sub & 8) ? hp0[0] : hp0[1];
                hp0[0] = k0 + dppmov<0x128>(s0);
                float k1 = (sub & 8) ? hp1[1] : hp1[0];
                float s1 = (sub & 8) ? hp1[0] : hp1[1];
                hp1[0] = k1 + dppmov<0x128>(s1);
            }
            hp0[0] += swz4f(hp0[0]);             // d-half join: lane bit 4 (DS)
            hp1[0] += swz4f(hp1[0]);
            float qs = g ? qwB : qwA, ws = g ? w2B : w2A;
            sc0 += ws / (1.f + __expf(-(qs + hp0[0])));
            sc1 += ws / (1.f + __expf(-(qs + hp1[0])));
        }
        // broadcast-sum over bits {1,2,8} (VALU DPP)
        sc0 += dppmov<0xB1>(sc0);
        sc0 += dppmov<0x4E>(sc0);
        sc0 += dppmov<0x128>(sc0);
        sc1 += dppmov<0xB1>(sc1);
        sc1 += dppmov<0x4E>(sc1);
        sc1 += dppmov<0x128>(sc1);
        float w0 = mv[0] ? __expf(sc0) : 0.f;    // deferred softmax: |sc| <= sum|W2|
        float w1 = mv[1] ? __expf(sc1) : 0.f;
        lloc += w0 + w1;
        #pragma unroll
        for (int j = 0; j < 4; ++j) {
            a8[2*j]     += w0 * (float)H[0][j].x + w1 * (float)H[1][j].x;
            a8[2*j + 1] += w0 * (float)H[0][j].y + w1 * (float)H[1][j].y;
        }
    };

    // ---- main loop: 3-deep rotating prefetch (loads 2 process-calls ahead) ----
    #pragma unroll 1
    for (int c = 0; c < 24; c += 3) {
        loadF(c + 2, FC, mvC);
        process(FA, mvA);                        // chunk c
        loadF(c + 3, FA, mvA);
        process(FB, mvB);                        // chunk c+1
        if (c + 4 < NCH) loadF(c + 4, FB, mvB);  // skipped only at c=21
        process(FC, mvC);                        // chunk c+2
    }
    process(FA, mvA);                            // chunk 24

    // ---- epilogue: reduce l over rowgroups; halving-reduce a8; store ----
    float l = lloc;
    l += __shfl_xor(l, 16);
    l += __shfl_xor(l, 32);
    #pragma unroll
    for (int i = 0; i < 4; ++i) {
        float kp = (rg & 1) ? a8[i + 4] : a8[i];
        float sd = (rg & 1) ? a8[i]     : a8[i + 4];
        a8[i] = kp + __shfl_xor(sd, 16);
    }
    #pragma unroll
    for (int i = 0; i < 2; ++i) {
        float kp = (rg & 2) ? a8[i + 2] : a8[i];
        float sd = (rg & 2) ? a8[i]     : a8[i + 2];
        a8[i] = kp + __shfl_xor(sd, 32);
    }
    int dl = sub * 8 + 4 * (rg & 1) + 2 * ((rg >> 1) & 1);
    float inv = 1.f / l;
    *(float2*)(out + (size_t)b * D_DIM + dl) = make_float2(a8[0] * inv, a8[1] * inv);
}

extern "C" void kernel_launch(void* const* d_in, const int* in_sizes, int n_in,
                              void* d_out, int out_size, void* d_ws, size_t ws_size,
                              hipStream_t stream) {
    const float* query = (const float*)d_in[0];
    const float* facts = (const float*)d_in[1];
    const int*   mask  = (const int*)d_in[2];   // harness delivers bool as int32
    const float* W1    = (const float*)d_in[3];
    const float* b1    = (const float*)d_in[4];
    const float* W2    = (const float*)d_in[5];
    // d_in[6] = b2: dropped (cancels in softmax ratio)
    float* out = (float*)d_out;
    (void)in_sizes; (void)n_in; (void)out_size; (void)d_ws; (void)ws_size;

    din_fused<<<dim3(B_DIM / 8), dim3(512), 0, stream>>>(
        query, facts, mask, W1, b1, W2, out);
}